// Round 1
// baseline (315.773 us; speedup 1.0000x reference)
//
#include <hip/hip_runtime.h>

#define Bn 4
#define Cn 256
#define Tn 4096

typedef unsigned short u16;
typedef __bf16 bf16x8 __attribute__((ext_vector_type(8)));
typedef float f32x4 __attribute__((ext_vector_type(4)));
typedef float f32x16 __attribute__((ext_vector_type(16)));
typedef u16 u16x8 __attribute__((ext_vector_type(8)));

__device__ __forceinline__ float b2f(u16 u) {
    union { unsigned int i; float f; } v;
    v.i = ((unsigned int)u) << 16;
    return v.f;
}
__device__ __forceinline__ u16 f2b(float f) {
    union { float f; unsigned int i; } v;
    v.f = f;
    unsigned int r = v.i + 0x7FFFu + ((v.i >> 16) & 1u);
    return (u16)(r >> 16);
}
__device__ __forceinline__ bf16x8 ones8() {
    union { u16 u[8]; bf16x8 v; } t;
    for (int j = 0; j < 8; j++) t.u[j] = 0x3F80;  // bf16 1.0
    return t.v;
}

// R11: drain-free barrier. __syncthreads() forces s_waitcnt vmcnt(0) before
// s_barrier, which drains just-issued global prefetches every iteration.
// Cross-wave visibility only needs LDS writes drained (lgkmcnt); prefetch
// registers are wave-private (compiler inserts counted vmcnt at their use).
__device__ __forceinline__ void barrier_nodrain() {
    asm volatile("s_waitcnt lgkmcnt(0)" ::: "memory");
    __builtin_amdgcn_s_barrier();
    asm volatile("" ::: "memory");
}

// pack two f32 -> one u32 of 2 bf16 (RTNE), single instruction
__device__ __forceinline__ unsigned int cvtpk(float lo, float hi) {
    unsigned int r;
    asm("v_cvt_pk_bf16_f32 %0, %1, %2" : "=v"(r) : "v"(lo), "v"(hi));
    return r;
}
// swap a.hi(lanes 32-63) <-> b.lo(lanes 0-31); both operands modified
__device__ __forceinline__ void permswap(unsigned int& a, unsigned int& b) {
    asm("v_permlane32_swap_b32 %0, %1" : "+v"(a), "+v"(b));
}

// ---------------------------------------------------------------------------
// Weight convert: five fp32 [C][C] weights -> contiguous bf16 regions in ws.
// Region 1 (Wq) pre-scaled by 1/16 (attention scale folded into q-proj).
// ---------------------------------------------------------------------------
__global__ __launch_bounds__(256) void cvt_kernel(
    const float* __restrict__ w0, const float* __restrict__ w1,
    const float* __restrict__ w2, const float* __restrict__ w3,
    const float* __restrict__ w4, u16* __restrict__ dst)
{
    int gid = blockIdx.x * 256 + threadIdx.x;
    int base = gid * 4;
    int region = base >> 16;
    int off = base & 65535;
    const float* src = region == 0 ? w0 : region == 1 ? w1
                     : region == 2 ? w2 : region == 3 ? w3 : w4;
    float sc = (region == 1) ? 0.0625f : 1.0f;
    float4 v = *(const float4*)(src + off);
    ushort4 o;
    o.x = f2b(v.x * sc); o.y = f2b(v.y * sc);
    o.z = f2b(v.z * sc); o.w = f2b(v.w * sc);
    *(ushort4*)(dst + base) = o;
}

// ---------------------------------------------------------------------------
// LN: h = x*m (f32 stats), ln -> lnT [B][T][C] bf16. Also emits xb = bf16
// masked-x in [B][C][T] for the final residual. 32 t-rows/block.
// ---------------------------------------------------------------------------
__global__ __launch_bounds__(256) void ln_kernel(
    const float* __restrict__ x, const float* __restrict__ mask,
    const float* __restrict__ gamma, const float* __restrict__ beta,
    u16* __restrict__ lnT, u16* __restrict__ xb)
{
    __shared__ __attribute__((aligned(16))) u16 tile[32][264];
    __shared__ float ssum[8][32], ssq[8][32], smu[32], srs[32];
    const int tid = threadIdx.x;
    const int b = blockIdx.y;
    const int t0 = blockIdx.x * 32;
    const int g = tid >> 5, tl = tid & 31;
    const int t = t0 + tl;
    const float mval = mask[b * Tn + t];
    float s = 0.f, s2 = 0.f;
    for (int c = g; c < Cn; c += 8) {
        float v = x[((size_t)(b * Cn + c)) * Tn + t] * mval;
        s += v; s2 += v * v;
        u16 vb = f2b(v);
        tile[tl][c] = vb;
        xb[((size_t)(b * Cn + c)) * Tn + t] = vb;
    }
    ssum[g][tl] = s; ssq[g][tl] = s2;
    __syncthreads();
    if (tid < 32) {
        float su = 0.f, sq = 0.f;
        for (int k = 0; k < 8; k++) { su += ssum[k][tid]; sq += ssq[k][tid]; }
        float mu = su * (1.f / Cn);
        float var = sq * (1.f / Cn) - mu * mu;
        var = fmaxf(var, 0.0f);
        smu[tid] = mu;
        srs[tid] = 1.0f / sqrtf(var + 1e-5f);
    }
    __syncthreads();
    for (int it = 0; it < 4; it++) {
        int idx = it * 256 + tid;
        int row = idx >> 5, c16 = idx & 31;
        float mu = smu[row], rs = srs[row];
        u16x8 ov;
        for (int j = 0; j < 8; j++) {
            int c = c16 * 8 + j;
            float h = b2f(tile[row][c]);
            float v = (h - mu) * rs * gamma[c] + beta[c];
            ov[j] = f2b(v);
        }
        *(u16x8*)(lnT + ((size_t)(b * Tn + t0 + row)) * Cn + c16 * 8) = ov;
    }
}

// ---------------------------------------------------------------------------
// Wp GEMM: Y[t][o] = sum_c A[t][c]*W[o][c], (acc+bias)*mask -> bf16.
// R11: register double-buffer prefetch + drain-free barriers (loads for
// k0+64 stay in flight across the barrier, hidden under MFMA).
// ---------------------------------------------------------------------------
__global__ __launch_bounds__(256) void wp_kernel(
    const u16* __restrict__ Xb, const u16* __restrict__ Wb,
    const float* __restrict__ bias, const float* __restrict__ mask,
    u16* __restrict__ Yout)
{
    __shared__ __attribute__((aligned(16))) u16 Al[128][72];
    __shared__ __attribute__((aligned(16))) u16 Bl[64][72];
    const int tid = threadIdx.x;
    const int b = blockIdx.z;
    const int m0 = blockIdx.x * 128;
    const int n0 = blockIdx.y * 64;
    const int wave = tid >> 6, lane = tid & 63;
    const int ln16 = lane & 15, quad = lane >> 4;
    const int wm = (wave & 1) * 64, wn = (wave >> 1) * 32;

    const u16* Abase = Xb + ((size_t)(b * Tn + m0)) * Cn;
    const u16* Bbase = Wb + (size_t)n0 * Cn;

    f32x4 acc[4][2];
    for (int i = 0; i < 4; i++)
        for (int j = 0; j < 2; j++) acc[i][j] = (f32x4){0.f, 0.f, 0.f, 0.f};

    uint4 pa[4], pb[2];
    auto ldA = [&](int k0) {
        for (int it = 0; it < 4; it++) {
            int idx = it * 256 + tid;
            int row = idx >> 3, gg = idx & 7;
            pa[it] = *(const uint4*)(Abase + (size_t)row * Cn + k0 + gg * 8);
        }
    };
    auto ldB = [&](int k0) {
        for (int it = 0; it < 2; it++) {
            int idx = it * 256 + tid;
            int row = idx >> 3, gg = idx & 7;
            pb[it] = *(const uint4*)(Bbase + (size_t)row * Cn + k0 + gg * 8);
        }
    };
    ldA(0); ldB(0);

    for (int k0 = 0; k0 < Cn; k0 += 64) {
        for (int it = 0; it < 4; it++) {
            int idx = it * 256 + tid;
            int row = idx >> 3, gg = idx & 7;
            *(uint4*)(&Al[row][gg * 8]) = pa[it];
        }
        for (int it = 0; it < 2; it++) {
            int idx = it * 256 + tid;
            int row = idx >> 3, gg = idx & 7;
            *(uint4*)(&Bl[row][gg * 8]) = pb[it];
        }
        if (k0 + 64 < Cn) { ldA(k0 + 64); ldB(k0 + 64); }
        barrier_nodrain();
        for (int kk = 0; kk < 2; kk++) {
            bf16x8 af[4], bfr[2];
            for (int i = 0; i < 4; i++)
                af[i] = *(const bf16x8*)(&Al[wm + i * 16 + ln16][kk * 32 + quad * 8]);
            for (int j = 0; j < 2; j++)
                bfr[j] = *(const bf16x8*)(&Bl[wn + j * 16 + ln16][kk * 32 + quad * 8]);
            for (int i = 0; i < 4; i++)
                for (int j = 0; j < 2; j++)
                    acc[i][j] = __builtin_amdgcn_mfma_f32_16x16x32_bf16(
                        af[i], bfr[j], acc[i][j], 0, 0, 0);
        }
        barrier_nodrain();
    }
    for (int i = 0; i < 4; i++) {
        for (int j = 0; j < 2; j++) {
            int nn = n0 + wn + j * 16 + ln16;
            for (int r = 0; r < 4; r++) {
                int tt = m0 + wm + i * 16 + quad * 4 + r;
                float val = acc[i][j][r] + bias[nn];
                val *= mask[b * Tn + tt];
                Yout[((size_t)(b * Tn + tt)) * Cn + nn] = f2b(val);
            }
        }
    }
}

// ---------------------------------------------------------------------------
// Fused q/k/v projections. which=z>>2 (0=q,1=k,2=v), b=z&3. v: LDS-transpose
// epilogue for coalesced [C][T] store. R11: prefetch + drain-free barriers.
// ---------------------------------------------------------------------------
__global__ __launch_bounds__(256) void qkv_kernel(
    const u16* __restrict__ h1T,
    const u16* __restrict__ Wq_, const float* __restrict__ bq_,
    const u16* __restrict__ Wk_, const float* __restrict__ bk_,
    const u16* __restrict__ Wv_, const float* __restrict__ bv_,
    const float* __restrict__ mask,
    u16* __restrict__ qO, u16* __restrict__ kO, u16* __restrict__ vO)
{
    __shared__ __attribute__((aligned(16))) u16 Al[128][72];
    __shared__ __attribute__((aligned(16))) u16 Bl[64][72];
    const int tid = threadIdx.x;
    const int z = blockIdx.z;
    const int which = z >> 2;
    const int b = z & 3;
    const u16* W = which == 0 ? Wq_ : which == 1 ? Wk_ : Wv_;
    const float* bi = which == 0 ? bq_ : which == 1 ? bk_ : bv_;
    const float bsc = which == 0 ? 0.0625f : 1.0f;
    const int m0 = blockIdx.x * 128;   // t
    const int n0 = blockIdx.y * 64;    // o
    const int wave = tid >> 6, lane = tid & 63;
    const int ln16 = lane & 15, quad = lane >> 4;
    const int wm = (wave & 1) * 64, wn = (wave >> 1) * 32;

    const u16* Abase = h1T + ((size_t)(b * Tn + m0)) * Cn;
    const u16* Bbase = W + (size_t)n0 * Cn;

    f32x4 acc[4][2];
    for (int i = 0; i < 4; i++)
        for (int j = 0; j < 2; j++) acc[i][j] = (f32x4){0.f, 0.f, 0.f, 0.f};

    uint4 pa[4], pb[2];
    auto ldA = [&](int k0) {
        for (int it = 0; it < 4; it++) {
            int idx = it * 256 + tid;
            int row = idx >> 3, gg = idx & 7;
            pa[it] = *(const uint4*)(Abase + (size_t)row * Cn + k0 + gg * 8);
        }
    };
    auto ldB = [&](int k0) {
        for (int it = 0; it < 2; it++) {
            int idx = it * 256 + tid;
            int row = idx >> 3, gg = idx & 7;
            pb[it] = *(const uint4*)(Bbase + (size_t)row * Cn + k0 + gg * 8);
        }
    };
    ldA(0); ldB(0);

    for (int k0 = 0; k0 < Cn; k0 += 64) {
        for (int it = 0; it < 4; it++) {
            int idx = it * 256 + tid;
            int row = idx >> 3, gg = idx & 7;
            *(uint4*)(&Al[row][gg * 8]) = pa[it];
        }
        for (int it = 0; it < 2; it++) {
            int idx = it * 256 + tid;
            int row = idx >> 3, gg = idx & 7;
            *(uint4*)(&Bl[row][gg * 8]) = pb[it];
        }
        if (k0 + 64 < Cn) { ldA(k0 + 64); ldB(k0 + 64); }
        barrier_nodrain();
        for (int kk = 0; kk < 2; kk++) {
            bf16x8 af[4], bfr[2];
            for (int i = 0; i < 4; i++)
                af[i] = *(const bf16x8*)(&Al[wm + i * 16 + ln16][kk * 32 + quad * 8]);
            for (int j = 0; j < 2; j++)
                bfr[j] = *(const bf16x8*)(&Bl[wn + j * 16 + ln16][kk * 32 + quad * 8]);
            for (int i = 0; i < 4; i++)
                for (int j = 0; j < 2; j++)
                    acc[i][j] = __builtin_amdgcn_mfma_f32_16x16x32_bf16(
                        af[i], bfr[j], acc[i][j], 0, 0, 0);
        }
        barrier_nodrain();
    }

    if (which < 2) {
        u16* Yo = which == 0 ? qO : kO;
        for (int i = 0; i < 4; i++) {
            for (int j = 0; j < 2; j++) {
                int nn = n0 + wn + j * 16 + ln16;
                for (int r = 0; r < 4; r++) {
                    int tt = m0 + wm + i * 16 + quad * 4 + r;
                    float val = acc[i][j][r] + bi[nn] * bsc;
                    val *= mask[b * Tn + tt];
                    Yo[((size_t)(b * Tn + tt)) * Cn + nn] = f2b(val);
                }
            }
        }
    } else {
        u16* vt = &Al[0][0];
        for (int i = 0; i < 4; i++) {
            for (int j = 0; j < 2; j++) {
                int nl = wn + j * 16 + ln16;
                for (int r = 0; r < 4; r++) {
                    int ml = wm + i * 16 + quad * 4 + r;
                    int tt = m0 + ml;
                    float val = acc[i][j][r] + bi[n0 + nl];
                    val *= mask[b * Tn + tt];
                    vt[nl * 136 + ml] = f2b(val);
                }
            }
        }
        barrier_nodrain();
        for (int itc = 0; itc < 4; itc++) {
            int cidx = itc * 256 + tid;
            int row = cidx >> 4;
            int ch = cidx & 15;
            u16x8 ov = *(const u16x8*)(vt + row * 136 + ch * 8);
            *(u16x8*)(vO + ((size_t)(b * Cn + n0 + row)) * Tn + m0 + ch * 8) = ov;
        }
    }
}

// ---------------------------------------------------------------------------
// Flash attention. 512 thr = 8 waves; wave owns 32 q-rows; 32x32x16 MFMA;
// fixed-max softmax (q pre-scaled 1/16, M=8 in negk); l via MFMA vs ones;
// register prefetch; kls/vls double-buffered, ONE barrier per iteration.
// R11: (a) drain-free barrier — prefetch global loads stay in flight across
// the barrier instead of being drained by __syncthreads' vmcnt(0);
// (b) T12 in-register P: S computed SWAPPED (mfma(K,Q): lane=q-row, r=s),
// per-s negk via broadcast f32x4 LDS reads, cvt_pk_bf16 + permlane32_swap
// assemble PV A-fragments in registers — pls LDS round-trip (and its ~4M
// bank-conflict cycles) removed, LDS 129KB -> 77KB; (c) setprio around MFMA.
// ---------------------------------------------------------------------------
__global__ __launch_bounds__(512, 2) void attn_kernel(
    const u16* __restrict__ qT, const u16* __restrict__ kT,
    const u16* __restrict__ vv, const float* __restrict__ mask,
    u16* __restrict__ PO01, u16* __restrict__ POx, float* __restrict__ pL)
{
    __shared__ __attribute__((aligned(16))) u16 kls[2][32][264];   // [s][c] x2
    __shared__ __attribute__((aligned(16))) u16 vls[2][256][40];   // [c][s] x2
    __shared__ __attribute__((aligned(16))) float nls[1024];
    const int tid = threadIdx.x;
    const int id = blockIdx.x;
    const int spl = id & 3;
    const int b = (id >> 2) & 3;
    const int qb = id >> 4;
    const int t0 = qb * 256;
    const int wave = tid >> 6, lane = tid & 63;
    const int ln32 = lane & 31, half = lane >> 5;
    const int sBeg = spl * (Tn / 4);
    const int nIter = (Tn / 4) / 32;        // 32

    for (int i = tid; i < 1024; i += 512)
        nls[i] = (1.0f - mask[b * Tn + sBeg + i]) * -1e8f - 8.0f;

    bf16x8 qf[16];
    {
        const u16* qp = qT + ((size_t)(b * Tn + t0 + wave * 32 + ln32)) * Cn + half * 8;
        for (int ks = 0; ks < 16; ks++) qf[ks] = *(const bf16x8*)(qp + ks * 16);
    }
    f32x16 acc[8], lac;
    for (int i = 0; i < 16; i++) lac[i] = 0.f;
    for (int nt = 0; nt < 8; nt++) acc[nt] = lac;
    const bf16x8 ones = ones8();

    uint4 kpre[2], vpre[2];
    auto loadK = [&](int s0) {
        for (int i = 0; i < 2; i++) {
            int idx = i * 512 + tid;
            kpre[i] = *(const uint4*)(kT + ((size_t)(b * Tn + s0 + (idx >> 5))) * Cn + (idx & 31) * 8);
        }
    };
    auto loadV = [&](int s0) {
        for (int i = 0; i < 2; i++) {
            int idx = i * 512 + tid;
            vpre[i] = *(const uint4*)(vv + ((size_t)(b * Cn + (idx >> 2))) * Tn + s0 + (idx & 3) * 8);
        }
    };
    loadK(sBeg);
    loadV(sBeg);

    for (int it = 0; it < nIter; it++) {
        const int cb = it & 1;
        // stage current tile into buffer cb (no pre-barrier: cb's previous
        // readers drained at the previous iteration's barrier)
        for (int i = 0; i < 2; i++) {
            int idx = i * 512 + tid;
            *(uint4*)(&kls[cb][idx >> 5][(idx & 31) * 8]) = kpre[i];
        }
        for (int i = 0; i < 2; i++) {
            int idx = i * 512 + tid;
            *(uint4*)(&vls[cb][idx >> 2][(idx & 3) * 8]) = vpre[i];
        }
        if (it + 1 < nIter) {
            loadK(sBeg + (it + 1) * 32);
            loadV(sBeg + (it + 1) * 32);
        }
        barrier_nodrain();                  // publish buffer cb; prefetch stays in flight

        // QK^T swapped: S'[r <-> s][col=ln32 <-> t] = sum_c K[s][c] Q[t][c]
        f32x16 S;
        for (int i = 0; i < 16; i++) S[i] = 0.f;
        __builtin_amdgcn_s_setprio(1);
        for (int ks = 0; ks < 16; ks++) {
            bf16x8 kf = *(const bf16x8*)(&kls[cb][ln32][ks * 16 + half * 8]);
            S = __builtin_amdgcn_mfma_f32_32x32x16_bf16(kf, qf[ks], S, 0, 0, 0);
        }
        __builtin_amdgcn_s_setprio(0);

        // exp with per-s negk: s = (r&3) + 8*(r>>2) + 4*half.
        // f32x4 broadcast read per r-quad (same addr within a half -> free).
        for (int g2 = 0; g2 < 4; g2++) {
            f32x4 nk = *(const f32x4*)(&nls[it * 32 + g2 * 8 + half * 4]);
            for (int j = 0; j < 4; j++) {
                int r = g2 * 4 + j;
                S[r] = __expf(S[r] + nk[j]);
            }
        }

        // T12 pack: A-frag word w of chunk needs (k=half*8+2w, +1) per lane.
        // half0 owns s{0-3,8-11,...}, half1 s{4-7,12-15,...}; permlane32_swap
        // (a.hi <-> b.lo) pairs each half with the partner's missing slice.
        union { unsigned int w[4]; bf16x8 v; } P0, P1;
        {
            unsigned int a0 = cvtpk(S[0], S[1]),  b0 = cvtpk(S[4], S[5]);
            permswap(a0, b0);
            unsigned int a1 = cvtpk(S[2], S[3]),  b1 = cvtpk(S[6], S[7]);
            permswap(a1, b1);
            P0.w[0] = a0; P0.w[1] = a1; P0.w[2] = b0; P0.w[3] = b1;
            unsigned int a2 = cvtpk(S[8], S[9]),  b2 = cvtpk(S[12], S[13]);
            permswap(a2, b2);
            unsigned int a3 = cvtpk(S[10], S[11]), b3 = cvtpk(S[14], S[15]);
            permswap(a3, b3);
            P1.w[0] = a2; P1.w[1] = a3; P1.w[2] = b2; P1.w[3] = b3;
        }
        bf16x8 pf0 = P0.v, pf1 = P1.v;

        __builtin_amdgcn_s_setprio(1);
        lac = __builtin_amdgcn_mfma_f32_32x32x16_bf16(pf0, ones, lac, 0, 0, 0);
        lac = __builtin_amdgcn_mfma_f32_32x32x16_bf16(pf1, ones, lac, 0, 0, 0);
        for (int nt = 0; nt < 8; nt++) {
            bf16x8 v0 = *(const bf16x8*)(&vls[cb][nt * 32 + ln32][half * 8]);
            bf16x8 v1 = *(const bf16x8*)(&vls[cb][nt * 32 + ln32][16 + half * 8]);
            acc[nt] = __builtin_amdgcn_mfma_f32_32x32x16_bf16(pf0, v0, acc[nt], 0, 0, 0);
            acc[nt] = __builtin_amdgcn_mfma_f32_32x32x16_bf16(pf1, v1, acc[nt], 0, 0, 0);
        }
        __builtin_amdgcn_s_setprio(0);
    }
    const size_t SZe = (size_t)Bn * Tn * Cn;
    u16* myPO = (spl < 2) ? PO01 + (size_t)spl * SZe
                          : POx + (size_t)(spl - 2) * SZe;
    for (int r = 0; r < 16; r++) {
        int trow = (r & 3) + 8 * (r >> 2) + 4 * half;
        int t = t0 + wave * 32 + trow;
        for (int nt = 0; nt < 8; nt++)
            myPO[((size_t)(b * Tn + t)) * Cn + nt * 32 + ln32] = f2b(acc[nt][r]);
        if (ln32 == 0) pL[(size_t)spl * (Bn * Tn) + b * Tn + t] = lac[r];
    }
}

// ---------------------------------------------------------------------------
// Final GEMM with fused split-combine: B-staging sums 4 unnormalized PO
// partials; epilogue applies 1/sum(l), bias, bf16 residual (xb), mask -> f32.
// R11: prefetch + drain-free barriers.
// ---------------------------------------------------------------------------
__global__ __launch_bounds__(256) void final_kernel(
    const u16* __restrict__ WoB, const float* __restrict__ bo,
    const u16* __restrict__ PO01, const u16* __restrict__ POx,
    const float* __restrict__ pL,
    const float* __restrict__ mask, const u16* __restrict__ xb,
    float* __restrict__ out)
{
    __shared__ __attribute__((aligned(16))) u16 Al[128][72];
    __shared__ __attribute__((aligned(16))) u16 Bl[64][72];
    __shared__ float rls[64];
    const int tid = threadIdx.x;
    const int b = blockIdx.z;
    const int m0 = blockIdx.x * 128;   // o
    const int n0 = blockIdx.y * 64;    // t
    const int wave = tid >> 6, lane = tid & 63;
    const int ln16 = lane & 15, quad = lane >> 4;
    const int wm = (wave & 1) * 64, wn = (wave >> 1) * 32;
    const size_t BT = (size_t)Bn * Tn;
    const size_t SZe = BT * Cn;

    if (tid < 64) {
        size_t R = (size_t)b * Tn + n0 + tid;
        float l = pL[R] + pL[BT + R] + pL[2 * BT + R] + pL[3 * BT + R];
        rls[tid] = 1.0f / fmaxf(l, 1e-30f);
    }

    f32x4 acc[4][2];
    for (int i = 0; i < 4; i++)
        for (int j = 0; j < 2; j++) acc[i][j] = (f32x4){0.f, 0.f, 0.f, 0.f};

    uint4 pa[4];
    u16x8 q0[2], q1[2], q2[2], q3[2];
    auto ldA = [&](int k0) {
        for (int it = 0; it < 4; it++) {
            int idx = it * 256 + tid;
            int row = idx >> 3, gg = idx & 7;
            pa[it] = *(const uint4*)(WoB + (size_t)(m0 + row) * Cn + k0 + gg * 8);
        }
    };
    auto ldB = [&](int k0) {
        for (int it = 0; it < 2; it++) {
            int idx = it * 256 + tid;
            int row = idx >> 3, gg = idx & 7;
            size_t base = ((size_t)b * Tn + n0 + row) * Cn + k0 + gg * 8;
            q0[it] = *(const u16x8*)(PO01 + base);
            q1[it] = *(const u16x8*)(PO01 + SZe + base);
            q2[it] = *(const u16x8*)(POx + base);
            q3[it] = *(const u16x8*)(POx + SZe + base);
        }
    };
    ldA(0); ldB(0);

    for (int k0 = 0; k0 < Cn; k0 += 64) {
        for (int it = 0; it < 4; it++) {
            int idx = it * 256 + tid;
            int row = idx >> 3, gg = idx & 7;
            *(uint4*)(&Al[row][gg * 8]) = pa[it];
        }
        for (int it = 0; it < 2; it++) {
            int idx = it * 256 + tid;
            int row = idx >> 3, gg = idx & 7;
            u16x8 o;
            for (int j = 0; j < 8; j++)
                o[j] = f2b(b2f(q0[it][j]) + b2f(q1[it][j]) + b2f(q2[it][j]) + b2f(q3[it][j]));
            *(u16x8*)(&Bl[row][gg * 8]) = o;
        }
        if (k0 + 64 < Cn) { ldA(k0 + 64); ldB(k0 + 64); }
        barrier_nodrain();
        for (int kk = 0; kk < 2; kk++) {
            bf16x8 af[4], bfr[2];
            for (int i = 0; i < 4; i++)
                af[i] = *(const bf16x8*)(&Al[wm + i * 16 + ln16][kk * 32 + quad * 8]);
            for (int j = 0; j < 2; j++)
                bfr[j] = *(const bf16x8*)(&Bl[wn + j * 16 + ln16][kk * 32 + quad * 8]);
            for (int i = 0; i < 4; i++)
                for (int j = 0; j < 2; j++)
                    acc[i][j] = __builtin_amdgcn_mfma_f32_16x16x32_bf16(
                        af[i], bfr[j], acc[i][j], 0, 0, 0);
        }
        barrier_nodrain();
    }
    for (int i = 0; i < 4; i++) {
        for (int j = 0; j < 2; j++) {
            int nl = wn + j * 16 + ln16;
            int tt = n0 + nl;
            float rl = rls[nl];
            float mk = mask[b * Tn + tt];
            for (int r = 0; r < 4; r++) {
                int oo = m0 + wm + i * 16 + quad * 4 + r;
                float val = acc[i][j][r] * rl + bo[oo];
                float xr = b2f(xb[((size_t)(b * Cn + oo)) * Tn + tt]);
                out[((size_t)(b * Cn + oo)) * Tn + tt] = (xr + val) * mk;
            }
        }
    }
}

extern "C" void kernel_launch(void* const* d_in, const int* in_sizes, int n_in,
                              void* d_out, int out_size, void* d_ws, size_t ws_size,
                              hipStream_t stream)
{
    const float* x     = (const float*)d_in[0];
    const float* xmask = (const float*)d_in[1];
    const float* gamma = (const float*)d_in[2];
    const float* beta  = (const float*)d_in[3];
    const float* Wp = (const float*)d_in[4];
    const float* bp = (const float*)d_in[5];
    const float* Wq = (const float*)d_in[6];
    const float* bq = (const float*)d_in[7];
    const float* Wk = (const float*)d_in[8];
    const float* bk = (const float*)d_in[9];
    const float* Wv = (const float*)d_in[10];
    const float* bv = (const float*)d_in[11];
    const float* Wo = (const float*)d_in[12];
    const float* bo = (const float*)d_in[13];
    float* out = (float*)d_out;

    u16* ws = (u16*)d_ws;
    const size_t SZ = (size_t)Bn * Tn * Cn;   // 4M elems
    const size_t WSZ = (size_t)Cn * Cn;
    const size_t BT = (size_t)Bn * Tn;
    u16* lnT = ws;            // slot0 [B][T][C]
    u16* h1T = ws + SZ;       // slot1
    u16* qTt = ws + 2 * SZ;
    u16* kTt = ws + 3 * SZ;
    u16* vB  = ws + 4 * SZ;   // [B][C][T]
    u16* wbf = ws + 5 * SZ;   // 5 bf16 weights
    u16* PO01 = ws;           // partials 0,1 overlay slots 0,1 (dead by attn)
    u16* POx  = ws + 5 * SZ + 5 * WSZ;   // partials 2,3
    float* pL = (float*)(POx + 2 * SZ);  // 4 x [B*T] f32
    u16* xb   = (u16*)(pL + 4 * BT);     // bf16 masked-x [B][C][T]

    u16* WpB = wbf;
    u16* WqB = wbf + WSZ;
    u16* WkB = wbf + 2 * WSZ;
    u16* WvB = wbf + 3 * WSZ;
    u16* WoB = wbf + 4 * WSZ;

    dim3 blk(256);
    cvt_kernel<<<dim3(320), blk, 0, stream>>>(Wp, Wq, Wk, Wv, Wo, wbf);
    ln_kernel<<<dim3(Tn / 32, Bn), blk, 0, stream>>>(x, xmask, gamma, beta, lnT, xb);
    wp_kernel<<<dim3(Tn / 128, Cn / 64, Bn), blk, 0, stream>>>(
        lnT, WpB, bp, xmask, h1T);
    qkv_kernel<<<dim3(Tn / 128, Cn / 64, 3 * Bn), blk, 0, stream>>>(
        h1T, WqB, bq, WkB, bk, WvB, bv, xmask, qTt, kTt, vB);
    attn_kernel<<<dim3(256), dim3(512), 0, stream>>>(
        qTt, kTt, vB, xmask, PO01, POx, pL);
    final_kernel<<<dim3(Cn / 128, Tn / 64, Bn), blk, 0, stream>>>(
        WoB, bo, PO01, POx, pL, xmask, xb, out);
}

// Round 3
// 244.857 us; speedup vs baseline: 1.2896x; 1.2896x over previous
//
#include <hip/hip_runtime.h>

#define Bn 4
#define Cn 256
#define Tn 4096

typedef unsigned short u16;
typedef __bf16 bf16x8 __attribute__((ext_vector_type(8)));
typedef float f32x4 __attribute__((ext_vector_type(4)));
typedef float f32x16 __attribute__((ext_vector_type(16)));
typedef u16 u16x8 __attribute__((ext_vector_type(8)));

__device__ __forceinline__ float b2f(u16 u) {
    union { unsigned int i; float f; } v;
    v.i = ((unsigned int)u) << 16;
    return v.f;
}
__device__ __forceinline__ u16 f2b(float f) {
    union { float f; unsigned int i; } v;
    v.f = f;
    unsigned int r = v.i + 0x7FFFu + ((v.i >> 16) & 1u);
    return (u16)(r >> 16);
}
__device__ __forceinline__ bf16x8 ones8() {
    union { u16 u[8]; bf16x8 v; } t;
    for (int j = 0; j < 8; j++) t.u[j] = 0x3F80;  // bf16 1.0
    return t.v;
}

// ---------------------------------------------------------------------------
// Weight convert: five fp32 [C][C] weights -> contiguous bf16 regions in ws.
// Region 1 (Wq) pre-scaled by 1/16 (attention scale folded into q-proj). (R10)
// ---------------------------------------------------------------------------
__global__ __launch_bounds__(256) void cvt_kernel(
    const float* __restrict__ w0, const float* __restrict__ w1,
    const float* __restrict__ w2, const float* __restrict__ w3,
    const float* __restrict__ w4, u16* __restrict__ dst)
{
    int gid = blockIdx.x * 256 + threadIdx.x;
    int base = gid * 4;
    int region = base >> 16;
    int off = base & 65535;
    const float* src = region == 0 ? w0 : region == 1 ? w1
                     : region == 2 ? w2 : region == 3 ? w3 : w4;
    float sc = (region == 1) ? 0.0625f : 1.0f;
    float4 v = *(const float4*)(src + off);
    ushort4 o;
    o.x = f2b(v.x * sc); o.y = f2b(v.y * sc);
    o.z = f2b(v.z * sc); o.w = f2b(v.w * sc);
    *(ushort4*)(dst + base) = o;
}

// ---------------------------------------------------------------------------
// LN: h = x*m (f32 stats), ln -> lnT [B][T][C] bf16. Also emits xb = bf16
// masked-x in [B][C][T] for the final residual. 32 t-rows/block. (R10)
// ---------------------------------------------------------------------------
__global__ __launch_bounds__(256) void ln_kernel(
    const float* __restrict__ x, const float* __restrict__ mask,
    const float* __restrict__ gamma, const float* __restrict__ beta,
    u16* __restrict__ lnT, u16* __restrict__ xb)
{
    __shared__ __attribute__((aligned(16))) u16 tile[32][264];
    __shared__ float ssum[8][32], ssq[8][32], smu[32], srs[32];
    const int tid = threadIdx.x;
    const int b = blockIdx.y;
    const int t0 = blockIdx.x * 32;
    const int g = tid >> 5, tl = tid & 31;
    const int t = t0 + tl;
    const float mval = mask[b * Tn + t];
    float s = 0.f, s2 = 0.f;
    for (int c = g; c < Cn; c += 8) {
        float v = x[((size_t)(b * Cn + c)) * Tn + t] * mval;
        s += v; s2 += v * v;
        u16 vb = f2b(v);
        tile[tl][c] = vb;
        xb[((size_t)(b * Cn + c)) * Tn + t] = vb;
    }
    ssum[g][tl] = s; ssq[g][tl] = s2;
    __syncthreads();
    if (tid < 32) {
        float su = 0.f, sq = 0.f;
        for (int k = 0; k < 8; k++) { su += ssum[k][tid]; sq += ssq[k][tid]; }
        float mu = su * (1.f / Cn);
        float var = sq * (1.f / Cn) - mu * mu;
        var = fmaxf(var, 0.0f);
        smu[tid] = mu;
        srs[tid] = 1.0f / sqrtf(var + 1e-5f);
    }
    __syncthreads();
    for (int it = 0; it < 4; it++) {
        int idx = it * 256 + tid;
        int row = idx >> 5, c16 = idx & 31;
        float mu = smu[row], rs = srs[row];
        u16x8 ov;
        for (int j = 0; j < 8; j++) {
            int c = c16 * 8 + j;
            float h = b2f(tile[row][c]);
            float v = (h - mu) * rs * gamma[c] + beta[c];
            ov[j] = f2b(v);
        }
        *(u16x8*)(lnT + ((size_t)(b * Tn + t0 + row)) * Cn + c16 * 8) = ov;
    }
}

// ---------------------------------------------------------------------------
// Wp GEMM: Y[t][o] = sum_c A[t][c]*W[o][c], (acc+bias)*mask -> bf16. (R10)
// ---------------------------------------------------------------------------
__global__ __launch_bounds__(256) void wp_kernel(
    const u16* __restrict__ Xb, const u16* __restrict__ Wb,
    const float* __restrict__ bias, const float* __restrict__ mask,
    u16* __restrict__ Yout)
{
    __shared__ __attribute__((aligned(16))) u16 Al[128][72];
    __shared__ __attribute__((aligned(16))) u16 Bl[64][72];
    const int tid = threadIdx.x;
    const int b = blockIdx.z;
    const int m0 = blockIdx.x * 128;
    const int n0 = blockIdx.y * 64;
    const int wave = tid >> 6, lane = tid & 63;
    const int ln16 = lane & 15, quad = lane >> 4;
    const int wm = (wave & 1) * 64, wn = (wave >> 1) * 32;

    const u16* Abase = Xb + ((size_t)(b * Tn + m0)) * Cn;
    const u16* Bbase = Wb + (size_t)n0 * Cn;

    f32x4 acc[4][2];
    for (int i = 0; i < 4; i++)
        for (int j = 0; j < 2; j++) acc[i][j] = (f32x4){0.f, 0.f, 0.f, 0.f};

    for (int k0 = 0; k0 < Cn; k0 += 64) {
        for (int it = 0; it < 4; it++) {
            int idx = it * 256 + tid;
            int row = idx >> 3, gg = idx & 7;
            *(uint4*)(&Al[row][gg * 8]) =
                *(const uint4*)(Abase + (size_t)row * Cn + k0 + gg * 8);
        }
        for (int it = 0; it < 2; it++) {
            int idx = it * 256 + tid;
            int row = idx >> 3, gg = idx & 7;
            *(uint4*)(&Bl[row][gg * 8]) =
                *(const uint4*)(Bbase + (size_t)row * Cn + k0 + gg * 8);
        }
        __syncthreads();
        for (int kk = 0; kk < 2; kk++) {
            bf16x8 af[4], bfr[2];
            for (int i = 0; i < 4; i++)
                af[i] = *(const bf16x8*)(&Al[wm + i * 16 + ln16][kk * 32 + quad * 8]);
            for (int j = 0; j < 2; j++)
                bfr[j] = *(const bf16x8*)(&Bl[wn + j * 16 + ln16][kk * 32 + quad * 8]);
            for (int i = 0; i < 4; i++)
                for (int j = 0; j < 2; j++)
                    acc[i][j] = __builtin_amdgcn_mfma_f32_16x16x32_bf16(
                        af[i], bfr[j], acc[i][j], 0, 0, 0);
        }
        __syncthreads();
    }
    for (int i = 0; i < 4; i++) {
        for (int j = 0; j < 2; j++) {
            int nn = n0 + wn + j * 16 + ln16;
            for (int r = 0; r < 4; r++) {
                int tt = m0 + wm + i * 16 + quad * 4 + r;
                float val = acc[i][j][r] + bias[nn];
                val *= mask[b * Tn + tt];
                Yout[((size_t)(b * Tn + tt)) * Cn + nn] = f2b(val);
            }
        }
    }
}

// ---------------------------------------------------------------------------
// Fused q/k/v projections. which=z>>2 (0=q,1=k,2=v), b=z&3. v: LDS-transpose
// epilogue for coalesced [C][T] store.
// R13: M-tile 128 -> 64 (grid 384 -> 3072 blocks, ~12 blocks/CU). R10 qkv was
// latency-bound (~1.5 blocks/CU, 4 serial K-steps gated on global latency);
// more resident blocks hide latency via TLP. ONLY change vs R10 this round
// (bisect: R12's simultaneous attn-pack change failed; attn reverted to R10).
// ---------------------------------------------------------------------------
__global__ __launch_bounds__(256) void qkv_kernel(
    const u16* __restrict__ h1T,
    const u16* __restrict__ Wq_, const float* __restrict__ bq_,
    const u16* __restrict__ Wk_, const float* __restrict__ bk_,
    const u16* __restrict__ Wv_, const float* __restrict__ bv_,
    const float* __restrict__ mask,
    u16* __restrict__ qO, u16* __restrict__ kO, u16* __restrict__ vO)
{
    __shared__ __attribute__((aligned(16))) u16 Al[64][72];
    __shared__ __attribute__((aligned(16))) u16 Bl[64][72];
    const int tid = threadIdx.x;
    const int z = blockIdx.z;
    const int which = z >> 2;
    const int b = z & 3;
    const u16* W = which == 0 ? Wq_ : which == 1 ? Wk_ : Wv_;
    const float* bi = which == 0 ? bq_ : which == 1 ? bk_ : bv_;
    const float bsc = which == 0 ? 0.0625f : 1.0f;
    const int m0 = blockIdx.x * 64;    // t
    const int n0 = blockIdx.y * 64;    // o
    const int wave = tid >> 6, lane = tid & 63;
    const int ln16 = lane & 15, quad = lane >> 4;
    const int wm = (wave & 1) * 32, wn = (wave >> 1) * 32;

    const u16* Abase = h1T + ((size_t)(b * Tn + m0)) * Cn;
    const u16* Bbase = W + (size_t)n0 * Cn;

    f32x4 acc[2][2];
    for (int i = 0; i < 2; i++)
        for (int j = 0; j < 2; j++) acc[i][j] = (f32x4){0.f, 0.f, 0.f, 0.f};

    for (int k0 = 0; k0 < Cn; k0 += 64) {
        for (int it = 0; it < 2; it++) {
            int idx = it * 256 + tid;
            int row = idx >> 3, gg = idx & 7;
            *(uint4*)(&Al[row][gg * 8]) =
                *(const uint4*)(Abase + (size_t)row * Cn + k0 + gg * 8);
        }
        for (int it = 0; it < 2; it++) {
            int idx = it * 256 + tid;
            int row = idx >> 3, gg = idx & 7;
            *(uint4*)(&Bl[row][gg * 8]) =
                *(const uint4*)(Bbase + (size_t)row * Cn + k0 + gg * 8);
        }
        __syncthreads();
        for (int kk = 0; kk < 2; kk++) {
            bf16x8 af[2], bfr[2];
            for (int i = 0; i < 2; i++)
                af[i] = *(const bf16x8*)(&Al[wm + i * 16 + ln16][kk * 32 + quad * 8]);
            for (int j = 0; j < 2; j++)
                bfr[j] = *(const bf16x8*)(&Bl[wn + j * 16 + ln16][kk * 32 + quad * 8]);
            for (int i = 0; i < 2; i++)
                for (int j = 0; j < 2; j++)
                    acc[i][j] = __builtin_amdgcn_mfma_f32_16x16x32_bf16(
                        af[i], bfr[j], acc[i][j], 0, 0, 0);
        }
        __syncthreads();
    }

    if (which < 2) {
        u16* Yo = which == 0 ? qO : kO;
        for (int i = 0; i < 2; i++) {
            for (int j = 0; j < 2; j++) {
                int nn = n0 + wn + j * 16 + ln16;
                for (int r = 0; r < 4; r++) {
                    int tt = m0 + wm + i * 16 + quad * 4 + r;
                    float val = acc[i][j][r] + bi[nn] * bsc;
                    val *= mask[b * Tn + tt];
                    Yo[((size_t)(b * Tn + tt)) * Cn + nn] = f2b(val);
                }
            }
        }
    } else {
        u16* vt = &Al[0][0];
        for (int i = 0; i < 2; i++) {
            for (int j = 0; j < 2; j++) {
                int nl = wn + j * 16 + ln16;
                for (int r = 0; r < 4; r++) {
                    int ml = wm + i * 16 + quad * 4 + r;
                    int tt = m0 + ml;
                    float val = acc[i][j][r] + bi[n0 + nl];
                    val *= mask[b * Tn + tt];
                    vt[nl * 72 + ml] = f2b(val);
                }
            }
        }
        __syncthreads();
        for (int itc = 0; itc < 2; itc++) {
            int cidx = itc * 256 + tid;
            int row = cidx >> 3;
            int ch = cidx & 7;
            u16x8 ov = *(const u16x8*)(vt + row * 72 + ch * 8);
            *(u16x8*)(vO + ((size_t)(b * Cn + n0 + row)) * Tn + m0 + ch * 8) = ov;
        }
    }
}

// ---------------------------------------------------------------------------
// Flash attention (R10 verbatim — verified 110.5 µs). 512 thr = 8 waves;
// wave owns 32 q-rows; 32x32x16 MFMA; fixed-max softmax (q pre-scaled 1/16,
// M=8 in negk); l via MFMA vs ones; register prefetch; kls/vls
// double-buffered -> ONE barrier per iteration; pls per-wave P transpose.
// ---------------------------------------------------------------------------
__global__ __launch_bounds__(512, 2) void attn_kernel(
    const u16* __restrict__ qT, const u16* __restrict__ kT,
    const u16* __restrict__ vv, const float* __restrict__ mask,
    u16* __restrict__ PO01, u16* __restrict__ POx, float* __restrict__ pL)
{
    __shared__ __attribute__((aligned(16))) u16 kls[2][32][264];   // [s][c] x2
    __shared__ __attribute__((aligned(16))) u16 vls[2][256][40];   // [c][s] x2
    __shared__ __attribute__((aligned(16))) u16 pls[8][32][40];    // per-wave P
    __shared__ float nls[1024];
    const int tid = threadIdx.x;
    const int id = blockIdx.x;
    const int spl = id & 3;
    const int b = (id >> 2) & 3;
    const int qb = id >> 4;
    const int t0 = qb * 256;
    const int wave = tid >> 6, lane = tid & 63;
    const int ln32 = lane & 31, half = lane >> 5;
    const int sBeg = spl * (Tn / 4);
    const int nIter = (Tn / 4) / 32;        // 32

    for (int i = tid; i < 1024; i += 512)
        nls[i] = (1.0f - mask[b * Tn + sBeg + i]) * -1e8f - 8.0f;

    bf16x8 qf[16];
    {
        const u16* qp = qT + ((size_t)(b * Tn + t0 + wave * 32 + ln32)) * Cn + half * 8;
        for (int ks = 0; ks < 16; ks++) qf[ks] = *(const bf16x8*)(qp + ks * 16);
    }
    f32x16 acc[8], lac;
    for (int i = 0; i < 16; i++) lac[i] = 0.f;
    for (int nt = 0; nt < 8; nt++) acc[nt] = lac;
    const bf16x8 ones = ones8();

    uint4 kpre[2], vpre[2];
    auto loadK = [&](int s0) {
        for (int i = 0; i < 2; i++) {
            int idx = i * 512 + tid;
            kpre[i] = *(const uint4*)(kT + ((size_t)(b * Tn + s0 + (idx >> 5))) * Cn + (idx & 31) * 8);
        }
    };
    auto loadV = [&](int s0) {
        for (int i = 0; i < 2; i++) {
            int idx = i * 512 + tid;
            vpre[i] = *(const uint4*)(vv + ((size_t)(b * Cn + (idx >> 2))) * Tn + s0 + (idx & 3) * 8);
        }
    };
    loadK(sBeg);
    loadV(sBeg);

    for (int it = 0; it < nIter; it++) {
        const int s0 = sBeg + it * 32;
        const int cb = it & 1;
        // stage current tile into buffer cb (no pre-barrier: cb's previous
        // readers drained at the intervening iteration's barrier)
        for (int i = 0; i < 2; i++) {
            int idx = i * 512 + tid;
            *(uint4*)(&kls[cb][idx >> 5][(idx & 31) * 8]) = kpre[i];
        }
        for (int i = 0; i < 2; i++) {
            int idx = i * 512 + tid;
            *(uint4*)(&vls[cb][idx >> 2][(idx & 3) * 8]) = vpre[i];
        }
        if (it + 1 < nIter) {
            loadK(s0 + 32);
            loadV(s0 + 32);
        }
        __syncthreads();                    // publish buffer cb
        const float negk = nls[it * 32 + ln32];

        f32x16 S;
        for (int i = 0; i < 16; i++) S[i] = 0.f;
        for (int ks = 0; ks < 16; ks++) {
            bf16x8 kf = *(const bf16x8*)(&kls[cb][ln32][ks * 16 + half * 8]);
            S = __builtin_amdgcn_mfma_f32_32x32x16_bf16(qf[ks], kf, S, 0, 0, 0);
        }
        for (int r = 0; r < 16; r++) S[r] = __expf(S[r] + negk);
        for (int r = 0; r < 16; r++) {
            int row = (r & 3) + 8 * (r >> 2) + 4 * half;
            pls[wave][row][ln32] = f2b(S[r]);
        }
        bf16x8 pf0 = *(const bf16x8*)(&pls[wave][ln32][half * 8]);
        bf16x8 pf1 = *(const bf16x8*)(&pls[wave][ln32][16 + half * 8]);
        lac = __builtin_amdgcn_mfma_f32_32x32x16_bf16(pf0, ones, lac, 0, 0, 0);
        lac = __builtin_amdgcn_mfma_f32_32x32x16_bf16(pf1, ones, lac, 0, 0, 0);
        for (int nt = 0; nt < 8; nt++) {
            bf16x8 v0 = *(const bf16x8*)(&vls[cb][nt * 32 + ln32][half * 8]);
            bf16x8 v1 = *(const bf16x8*)(&vls[cb][nt * 32 + ln32][16 + half * 8]);
            acc[nt] = __builtin_amdgcn_mfma_f32_32x32x16_bf16(pf0, v0, acc[nt], 0, 0, 0);
            acc[nt] = __builtin_amdgcn_mfma_f32_32x32x16_bf16(pf1, v1, acc[nt], 0, 0, 0);
        }
    }
    const size_t SZe = (size_t)Bn * Tn * Cn;
    u16* myPO = (spl < 2) ? PO01 + (size_t)spl * SZe
                          : POx + (size_t)(spl - 2) * SZe;
    for (int r = 0; r < 16; r++) {
        int trow = (r & 3) + 8 * (r >> 2) + 4 * half;
        int t = t0 + wave * 32 + trow;
        for (int nt = 0; nt < 8; nt++)
            myPO[((size_t)(b * Tn + t)) * Cn + nt * 32 + ln32] = f2b(acc[nt][r]);
        if (ln32 == 0) pL[(size_t)spl * (Bn * Tn) + b * Tn + t] = lac[r];
    }
}

// ---------------------------------------------------------------------------
// Final GEMM with fused split-combine: B-staging sums 4 unnormalized PO
// partials; epilogue applies 1/sum(l), bias, bf16 residual (xb), mask -> f32.
// (R10)
// ---------------------------------------------------------------------------
__global__ __launch_bounds__(256) void final_kernel(
    const u16* __restrict__ WoB, const float* __restrict__ bo,
    const u16* __restrict__ PO01, const u16* __restrict__ POx,
    const float* __restrict__ pL,
    const float* __restrict__ mask, const u16* __restrict__ xb,
    float* __restrict__ out)
{
    __shared__ __attribute__((aligned(16))) u16 Al[128][72];
    __shared__ __attribute__((aligned(16))) u16 Bl[64][72];
    __shared__ float rls[64];
    const int tid = threadIdx.x;
    const int b = blockIdx.z;
    const int m0 = blockIdx.x * 128;   // o
    const int n0 = blockIdx.y * 64;    // t
    const int wave = tid >> 6, lane = tid & 63;
    const int ln16 = lane & 15, quad = lane >> 4;
    const int wm = (wave & 1) * 64, wn = (wave >> 1) * 32;
    const size_t BT = (size_t)Bn * Tn;
    const size_t SZe = BT * Cn;

    if (tid < 64) {
        size_t R = (size_t)b * Tn + n0 + tid;
        float l = pL[R] + pL[BT + R] + pL[2 * BT + R] + pL[3 * BT + R];
        rls[tid] = 1.0f / fmaxf(l, 1e-30f);
    }

    f32x4 acc[4][2];
    for (int i = 0; i < 4; i++)
        for (int j = 0; j < 2; j++) acc[i][j] = (f32x4){0.f, 0.f, 0.f, 0.f};

    for (int k0 = 0; k0 < Cn; k0 += 64) {
        for (int it = 0; it < 4; it++) {
            int idx = it * 256 + tid;
            int row = idx >> 3, gg = idx & 7;
            *(uint4*)(&Al[row][gg * 8]) =
                *(const uint4*)(WoB + (size_t)(m0 + row) * Cn + k0 + gg * 8);
        }
        for (int it = 0; it < 2; it++) {
            int idx = it * 256 + tid;
            int row = idx >> 3, gg = idx & 7;
            size_t base = ((size_t)b * Tn + n0 + row) * Cn + k0 + gg * 8;
            u16x8 a0 = *(const u16x8*)(PO01 + base);
            u16x8 a1 = *(const u16x8*)(PO01 + SZe + base);
            u16x8 a2 = *(const u16x8*)(POx + base);
            u16x8 a3 = *(const u16x8*)(POx + SZe + base);
            u16x8 o;
            for (int j = 0; j < 8; j++)
                o[j] = f2b(b2f(a0[j]) + b2f(a1[j]) + b2f(a2[j]) + b2f(a3[j]));
            *(u16x8*)(&Bl[row][gg * 8]) = o;
        }
        __syncthreads();
        for (int kk = 0; kk < 2; kk++) {
            bf16x8 af[4], bfr[2];
            for (int i = 0; i < 4; i++)
                af[i] = *(const bf16x8*)(&Al[wm + i * 16 + ln16][kk * 32 + quad * 8]);
            for (int j = 0; j < 2; j++)
                bfr[j] = *(const bf16x8*)(&Bl[wn + j * 16 + ln16][kk * 32 + quad * 8]);
            for (int i = 0; i < 4; i++)
                for (int j = 0; j < 2; j++)
                    acc[i][j] = __builtin_amdgcn_mfma_f32_16x16x32_bf16(
                        af[i], bfr[j], acc[i][j], 0, 0, 0);
        }
        __syncthreads();
    }
    for (int i = 0; i < 4; i++) {
        for (int j = 0; j < 2; j++) {
            int nl = wn + j * 16 + ln16;
            int tt = n0 + nl;
            float rl = rls[nl];
            float mk = mask[b * Tn + tt];
            for (int r = 0; r < 4; r++) {
                int oo = m0 + wm + i * 16 + quad * 4 + r;
                float val = acc[i][j][r] * rl + bo[oo];
                float xr = b2f(xb[((size_t)(b * Cn + oo)) * Tn + tt]);
                out[((size_t)(b * Cn + oo)) * Tn + tt] = (xr + val) * mk;
            }
        }
    }
}

extern "C" void kernel_launch(void* const* d_in, const int* in_sizes, int n_in,
                              void* d_out, int out_size, void* d_ws, size_t ws_size,
                              hipStream_t stream)
{
    const float* x     = (const float*)d_in[0];
    const float* xmask = (const float*)d_in[1];
    const float* gamma = (const float*)d_in[2];
    const float* beta  = (const float*)d_in[3];
    const float* Wp = (const float*)d_in[4];
    const float* bp = (const float*)d_in[5];
    const float* Wq = (const float*)d_in[6];
    const float* bq = (const float*)d_in[7];
    const float* Wk = (const float*)d_in[8];
    const float* bk = (const float*)d_in[9];
    const float* Wv = (const float*)d_in[10];
    const float* bv = (const float*)d_in[11];
    const float* Wo = (const float*)d_in[12];
    const float* bo = (const float*)d_in[13];
    float* out = (float*)d_out;

    u16* ws = (u16*)d_ws;
    const size_t SZ = (size_t)Bn * Tn * Cn;   // 4M elems
    const size_t WSZ = (size_t)Cn * Cn;
    const size_t BT = (size_t)Bn * Tn;
    u16* lnT = ws;            // slot0 [B][T][C]
    u16* h1T = ws + SZ;       // slot1
    u16* qTt = ws + 2 * SZ;
    u16* kTt = ws + 3 * SZ;
    u16* vB  = ws + 4 * SZ;   // [B][C][T]
    u16* wbf = ws + 5 * SZ;   // 5 bf16 weights
    u16* PO01 = ws;           // partials 0,1 overlay slots 0,1 (dead by attn)
    u16* POx  = ws + 5 * SZ + 5 * WSZ;   // partials 2,3
    float* pL = (float*)(POx + 2 * SZ);  // 4 x [B*T] f32
    u16* xb   = (u16*)(pL + 4 * BT);     // bf16 masked-x [B][C][T]

    u16* WpB = wbf;
    u16* WqB = wbf + WSZ;
    u16* WkB = wbf + 2 * WSZ;
    u16* WvB = wbf + 3 * WSZ;
    u16* WoB = wbf + 4 * WSZ;

    dim3 blk(256);
    cvt_kernel<<<dim3(320), blk, 0, stream>>>(Wp, Wq, Wk, Wv, Wo, wbf);
    ln_kernel<<<dim3(Tn / 32, Bn), blk, 0, stream>>>(x, xmask, gamma, beta, lnT, xb);
    wp_kernel<<<dim3(Tn / 128, Cn / 64, Bn), blk, 0, stream>>>(
        lnT, WpB, bp, xmask, h1T);
    qkv_kernel<<<dim3(Tn / 64, Cn / 64, 3 * Bn), blk, 0, stream>>>(
        h1T, WqB, bq, WkB, bk, WvB, bv, xmask, qTt, kTt, vB);
    attn_kernel<<<dim3(256), dim3(512), 0, stream>>>(
        qTt, kTt, vB, xmask, PO01, POx, pL);
    final_kernel<<<dim3(Cn / 128, Tn / 64, Bn), blk, 0, stream>>>(
        WoB, bo, PO01, POx, pL, xmask, xb, out);
}